// Round 1
// baseline (3975.684 us; speedup 1.0000x reference)
//
#include <hip/hip_runtime.h>
#include <hip/hip_bf16.h>

// GRU-D layer: B=256, T=512, D=128, H=256, fp32.
// Phase 1: xg = x @ Wg + bg  (g in {z,r,h}) -- parallel GEMM.
//          xh -> d_out (read at step t, then overwritten by h_t: safe).
//          xz, xr -> d_ws (fp32 if ws_size allows, else bf16).
// Phase 2: persistent scan kernel, 1 block per batch (256 blocks x 512 thr),
//          U streamed from L2 each step (768 KB/step/CU -> ~3 ms bound).

static constexpr int Bb = 256;
static constexpr int Tt = 512;
static constexpr int Dd = 128;
static constexpr int Hh = 256;

// ---------------------------------------------------------------------------
// Phase 1: C[64-row tile, 256] = x_tile[64,128] @ W[128,256] + bias
// 256 threads: ty=tid>>5 (8 row-groups of 8), tx=tid&31 (32 col-groups of 8).
// LDS: x transposed [k][row] (pad 68 keeps float4 alignment + conflict-free
// scalar writes), W staged in 16-row slabs.
// ---------------------------------------------------------------------------
template<bool BF16OUT>
__global__ __launch_bounds__(256) void proj_kernel(
    const float* __restrict__ x, const float* __restrict__ W,
    const float* __restrict__ bias, void* __restrict__ outv)
{
  __shared__ float xT[Dd][68];    // [k][row], 68-f32 stride: 16B-aligned rows
  __shared__ float wS[16][Hh];    // W k-slab

  const int tid = threadIdx.x;
  const int ty = tid >> 5;        // 0..7  -> rows ty*8..ty*8+7
  const int tx = tid & 31;        // 0..31 -> cols tx*8..tx*8+7
  const size_t brow = (size_t)blockIdx.x * 64;
  const float* xp = x + brow * Dd;

  // stage x tile 64x128 (float4 global reads; LDS writes conflict-free:
  // consecutive lanes -> consecutive rows -> consecutive banks)
  #pragma unroll
  for (int it = 0; it < 8; ++it) {
    int idx = it * 256 + tid;     // 0..2047
    int row = idx & 63;
    int kq  = idx >> 6;           // 0..31
    float4 v = *(const float4*)(xp + row * Dd + kq * 4);
    xT[kq * 4 + 0][row] = v.x;
    xT[kq * 4 + 1][row] = v.y;
    xT[kq * 4 + 2][row] = v.z;
    xT[kq * 4 + 3][row] = v.w;
  }

  float bv[8];
  *(float4*)&bv[0] = *(const float4*)(bias + tx * 8);
  *(float4*)&bv[4] = *(const float4*)(bias + tx * 8 + 4);

  float acc[8][8];
  #pragma unroll
  for (int i = 0; i < 8; ++i)
    #pragma unroll
    for (int jj = 0; jj < 8; ++jj) acc[i][jj] = 0.f;

  for (int s = 0; s < 8; ++s) {
    // stage W slab s (16 k-rows x 256 cols)
    #pragma unroll
    for (int it = 0; it < 4; ++it) {
      int idx = it * 256 + tid;   // 0..1023 float4 units
      int kr = idx >> 6;          // 0..15
      int cq = idx & 63;          // 0..63
      *(float4*)&wS[kr][cq * 4] =
          *(const float4*)(W + (size_t)(s * 16 + kr) * Hh + cq * 4);
    }
    __syncthreads();

    #pragma unroll
    for (int kk = 0; kk < 16; ++kk) {
      const int k = s * 16 + kk;
      float xv[8], wv[8];
      *(float4*)&xv[0] = *(const float4*)&xT[k][ty * 8];      // broadcast
      *(float4*)&xv[4] = *(const float4*)&xT[k][ty * 8 + 4];
      *(float4*)&wv[0] = *(const float4*)&wS[kk][tx * 8];
      *(float4*)&wv[4] = *(const float4*)&wS[kk][tx * 8 + 4];
      #pragma unroll
      for (int i = 0; i < 8; ++i)
        #pragma unroll
        for (int jj = 0; jj < 8; ++jj)
          acc[i][jj] = fmaf(xv[i], wv[jj], acc[i][jj]);
    }
    __syncthreads();
  }

  // epilogue: bias + store
  if (!BF16OUT) {
    float* of = (float*)outv;
    #pragma unroll
    for (int i = 0; i < 8; ++i) {
      size_t ro = (brow + (size_t)ty * 8 + i) * Hh + tx * 8;
      float4 a{acc[i][0] + bv[0], acc[i][1] + bv[1],
               acc[i][2] + bv[2], acc[i][3] + bv[3]};
      float4 c{acc[i][4] + bv[4], acc[i][5] + bv[5],
               acc[i][6] + bv[6], acc[i][7] + bv[7]};
      *(float4*)(of + ro) = a;
      *(float4*)(of + ro + 4) = c;
    }
  } else {
    __hip_bfloat16* ob = (__hip_bfloat16*)outv;
    #pragma unroll
    for (int i = 0; i < 8; ++i) {
      size_t ro = (brow + (size_t)ty * 8 + i) * Hh + tx * 8;
      __hip_bfloat16 tmp[8];
      #pragma unroll
      for (int jj = 0; jj < 8; ++jj)
        tmp[jj] = __float2bfloat16(acc[i][jj] + bv[jj]);
      *(uint4*)(ob + ro) = *(uint4*)tmp;   // 16B packed store
    }
  }
}

// ---------------------------------------------------------------------------
// Phase 2: persistent scan. 1 block = 1 batch. 512 threads:
//   j = tid&255 (output column), half = tid>>8 (k-split over [0,128)/[128,256)).
// Per step: h_dec -> LDS; zr-GEMM (partials via LDS); gates; rh -> LDS;
// h-GEMM; combine; write h_t. 5 barriers/step. U streamed from L2.
// ---------------------------------------------------------------------------
template<bool PROJBF16>
__global__ __launch_bounds__(512) void gru_scan(
    const void* __restrict__ xz_v, const void* __restrict__ xr_v,
    const float* __restrict__ hdecay,
    const float* __restrict__ Uz, const float* __restrict__ Ur,
    const float* __restrict__ Uh, float* __restrict__ out)
{
  const int b    = blockIdx.x;
  const int tid  = threadIdx.x;
  const int j    = tid & (Hh - 1);
  const int half = tid >> 8;        // wave-uniform (waves 0-3 vs 4-7)
  const int k0   = half << 7;       // 0 or 128

  __shared__ float h_lds[Hh];
  __shared__ float hdec_lds[Hh];
  __shared__ float rh_lds[Hh];
  __shared__ float pz[2][Hh];
  __shared__ float pr[2][Hh];
  __shared__ float ph[2][Hh];

  if (half == 0) h_lds[j] = 0.f;    // h0 = 0; only (half0,j) reads it at t=0

  const float* xzf = (const float*)xz_v;
  const float* xrf = (const float*)xr_v;
  const __hip_bfloat16* xzb = (const __hip_bfloat16*)xz_v;
  const __hip_bfloat16* xrb = (const __hip_bfloat16*)xr_v;

  float z = 0.f, r = 0.f, xzt = 0.f, xrt = 0.f, xht = 0.f;

  for (int t = 0; t < Tt; ++t) {
    const size_t base = ((size_t)b * Tt + t) * Hh;

    if (half == 0) {
      float dec = hdecay[b * Tt + t];        // uniform -> s_load
      hdec_lds[j] = dec * h_lds[j];
      // prefetch this step's projections (consumed after the zr GEMM)
      if (PROJBF16) {
        xzt = __bfloat162float(xzb[base + j]);
        xrt = __bfloat162float(xrb[base + j]);
      } else {
        xzt = xzf[base + j];
        xrt = xrf[base + j];
      }
      xht = out[base + j];                   // xh lives in d_out
    }
    __syncthreads();

    // ---- z/r GEMM over own k-range, 8-deep load batching ----
    float az = 0.f, ar = 0.f;
    {
      const float* uzp = Uz + (size_t)k0 * Hh + j;
      const float* urp = Ur + (size_t)k0 * Hh + j;
      #pragma unroll 2
      for (int kk = 0; kk < 128; kk += 8) {
        float hdv[8];
        *(float4*)&hdv[0] = *(const float4*)&hdec_lds[k0 + kk];      // bcast
        *(float4*)&hdv[4] = *(const float4*)&hdec_lds[k0 + kk + 4];
        float uzv[8], urv[8];
        #pragma unroll
        for (int u = 0; u < 8; ++u) {
          uzv[u] = uzp[(size_t)(kk + u) * Hh];
          urv[u] = urp[(size_t)(kk + u) * Hh];
        }
        #pragma unroll
        for (int u = 0; u < 8; ++u) {
          az = fmaf(hdv[u], uzv[u], az);
          ar = fmaf(hdv[u], urv[u], ar);
        }
      }
    }
    pz[half][j] = az;
    pr[half][j] = ar;
    __syncthreads();

    if (half == 0) {
      float zs = xzt + pz[0][j] + pz[1][j];
      float rs = xrt + pr[0][j] + pr[1][j];
      z = 1.f / (1.f + __expf(-zs));
      r = 1.f / (1.f + __expf(-rs));
      rh_lds[j] = r * hdec_lds[j];
    }
    __syncthreads();

    // ---- h GEMM ----
    float ah = 0.f;
    {
      const float* uhp = Uh + (size_t)k0 * Hh + j;
      #pragma unroll 2
      for (int kk = 0; kk < 128; kk += 8) {
        float rhv[8];
        *(float4*)&rhv[0] = *(const float4*)&rh_lds[k0 + kk];
        *(float4*)&rhv[4] = *(const float4*)&rh_lds[k0 + kk + 4];
        float uhv[8];
        #pragma unroll
        for (int u = 0; u < 8; ++u) uhv[u] = uhp[(size_t)(kk + u) * Hh];
        #pragma unroll
        for (int u = 0; u < 8; ++u) ah = fmaf(rhv[u], uhv[u], ah);
      }
    }
    ph[half][j] = ah;
    __syncthreads();

    if (half == 0) {
      float hs = xht + ph[0][j] + ph[1][j];
      // tanh via exp, overflow-safe
      float e  = __expf(-2.f * fabsf(hs));
      float m  = (1.f - e) / (1.f + e);
      float hp = copysignf(m, hs);
      float hd = hdec_lds[j];
      float hn = (1.f - z) * hd + z * hp;
      out[base + j] = hn;
      h_lds[j] = hn;
    }
    __syncthreads();
  }
}

// ---------------------------------------------------------------------------
extern "C" void kernel_launch(void* const* d_in, const int* in_sizes, int n_in,
                              void* d_out, int out_size, void* d_ws, size_t ws_size,
                              hipStream_t stream) {
  const float* x   = (const float*)d_in[0];
  const float* hdc = (const float*)d_in[1];
  const float* Wr  = (const float*)d_in[2];
  const float* Wz  = (const float*)d_in[3];
  const float* Wh  = (const float*)d_in[4];
  const float* Ur  = (const float*)d_in[5];
  const float* Uz  = (const float*)d_in[6];
  const float* Uh  = (const float*)d_in[7];
  const float* br  = (const float*)d_in[8];
  const float* bz  = (const float*)d_in[9];
  const float* bh  = (const float*)d_in[10];
  float* out = (float*)d_out;

  const size_t bth = (size_t)Bb * Tt * Hh;   // 33,554,432 elements
  dim3 pgrid(2048), pblk(256);

  // xh -> d_out (always fp32)
  proj_kernel<false><<<pgrid, pblk, 0, stream>>>(x, Wh, bh, (void*)out);

  if (ws_size >= bth * 2 * sizeof(float)) {
    float* wsz = (float*)d_ws;
    float* wsr = wsz + bth;
    proj_kernel<false><<<pgrid, pblk, 0, stream>>>(x, Wz, bz, (void*)wsz);
    proj_kernel<false><<<pgrid, pblk, 0, stream>>>(x, Wr, br, (void*)wsr);
    gru_scan<false><<<dim3(Bb), dim3(512), 0, stream>>>(
        (const void*)wsz, (const void*)wsr, hdc, Uz, Ur, Uh, out);
  } else if (ws_size >= bth * 2 * sizeof(__hip_bfloat16)) {
    __hip_bfloat16* wsz = (__hip_bfloat16*)d_ws;
    __hip_bfloat16* wsr = wsz + bth;
    proj_kernel<true><<<pgrid, pblk, 0, stream>>>(x, Wz, bz, (void*)wsz);
    proj_kernel<true><<<pgrid, pblk, 0, stream>>>(x, Wr, br, (void*)wsr);
    gru_scan<true><<<dim3(Bb), dim3(512), 0, stream>>>(
        (const void*)wsz, (const void*)wsr, hdc, Uz, Ur, Uh, out);
  }
  // else: workspace too small for any staging path (unexpected; would fail
  // validation loudly rather than corrupt memory)
}